// Round 7
// baseline (259.318 us; speedup 1.0000x reference)
//
#include <hip/hip_runtime.h>

// cost[b,dd,ii,j,c,uv] = (bounds? x[b,c,uv, ii+d*(4-u), j+d*(4-v)] : 0) * mask[b,uv,ii,j]
// d = dd-4, u=uv/9, v=uv%9.  out = cost (b,9,96,96,324) flat, then ctr = x[:,:,40,:,:].
//
// v7 = R3 structure (XCD-band swizzle + vectorized 4x4 phase 1 + NT stores)
// with ONE variable changed: barrier-group granularity. 256-thread blocks,
// JB=16 -> LDS 23.3 KB -> 6 blocks/CU (same 24 waves/CU as R3, but 6
// independent barrier groups instead of 3). Tests whether the load-drain /
// store-burst convoy at each __syncthreads is the residual stall: more
// independent groups per CU => loads of one group overlap stores of another.

#define NAA 81
#define H 96
#define W 96
#define NC 4
#define ND 9
#define PLANE 9216          // 96*96
#define NR 324              // rows = c*81+uv
#define JB 16               // j per block
#define NJC 6               // j-chunks per row
#define OUTROW 31104        // W*NR
#define CTR_OFF 53747712LL  // 2*9*96*96*324
#define XTOT 5971968        // total floats in x
#define SUBV (JB * NR / 4)  // 1296 vec4 stores per block

typedef float f32x4 __attribute__((ext_vector_type(4)));
typedef f32x4 __attribute__((aligned(4))) f32x4u;   // 4B-aligned vector load

__global__ __launch_bounds__(256, 6)
void build_cost_kernel(const float* __restrict__ x, const float* __restrict__ mask,
                       float* __restrict__ out) {
    __shared__ __align__(16) float xs[JB * NR];   // xs[jj*NR + row]  (20,736 B)
    __shared__ __align__(16) int   lut[2 * NR];   // per row: {xb_or_-1, (mb<<6)|(s+16)}

    // ---- XCD-band swizzle decode (bijective: 10368 = 8 XCD * 1296) ----
    const int D   = blockIdx.x;      // 0..10367
    const int xcd = D & 7;           // target XCD (HW round-robin over dispatch id)
    const int s_  = D >> 3;          // 0..1295: slot within XCD
    const int b   = s_ / 648;        // slowest: batch
    const int w_  = s_ - 648 * b;    // 0..647
    const int dd  = w_ / 72;         // slow: disparity 0..8
    const int r_  = w_ - 72 * dd;
    const int jc  = r_ / 12;         // mid: j-chunk 0..5
    const int iio = r_ - 12 * jc;    // fast: ii within band
    const int ii  = 12 * xcd + iio;  // spatial row
    const int j0  = JB * jc;
    const int d   = dd - 4;
    const int tid = threadIdx.x;

    // ---- phase 0: packed per-row LUT (324 rows) ----
    for (int row = tid; row < NR; row += 256) {
        int c  = row / 81;
        int uv = row - 81 * c;
        int u  = uv / 9;
        int v  = uv - 9 * u;
        int ri = ii + d * (4 - u);
        int xb = ((b * NC + c) * NAA + uv) * PLANE + ri * W;
        int mb = ((b * NAA + uv) * H + ii) * W;
        int s  = d * (4 - v);
        lut[2 * row]     = ((unsigned)ri < (unsigned)H) ? xb : -1;
        lut[2 * row + 1] = (mb << 6) | (s + 16);
    }
    __syncthreads();

    // ---- phase 1: stage 4x4 tiles. item = (row-quad rq, j-quad j4) ----
    for (int idx = tid; idx < NAA * 4; idx += 256) {   // 324 items
        int rq = idx >> 2;               // row quad 0..80
        int j4 = idx & 3;                // j quad 0..3
        int jb = 4 * j4;
        int4 P0 = *(const int4*)&lut[8 * rq];       // rows 4rq, 4rq+1
        int4 P1 = *(const int4*)&lut[8 * rq + 4];   // rows 4rq+2, 4rq+3

        auto ld = [&](int xb, int B) -> f32x4 {
            int s    = (B & 63) - 16;
            int col0 = j0 + jb + s;
            int a0   = xb + col0;
            int addr = min(max(a0, 0), XTOT - 4);
            f32x4 xv = *(const f32x4u*)(x + addr);
            f32x4 mv = *(const f32x4*)(mask + (B >> 6) + j0 + jb);
            f32x4 r;
            bool rv = (xb >= 0);
            r.x = (rv && (unsigned)(col0 + 0) < (unsigned)W) ? xv.x * mv.x : 0.0f;
            r.y = (rv && (unsigned)(col0 + 1) < (unsigned)W) ? xv.y * mv.y : 0.0f;
            r.z = (rv && (unsigned)(col0 + 2) < (unsigned)W) ? xv.z * mv.z : 0.0f;
            r.w = (rv && (unsigned)(col0 + 3) < (unsigned)W) ? xv.w * mv.w : 0.0f;
            return r;
        };

        f32x4 v0 = ld(P0.x, P0.y);
        f32x4 v1 = ld(P0.z, P0.w);
        f32x4 v2 = ld(P1.x, P1.y);
        f32x4 v3 = ld(P1.z, P1.w);

        // transpose 4x4 in registers; column t -> rows 4rq..4rq+3 at jj=jb+t
        float* base = &xs[4 * rq];
        f32x4 w0 = {v0.x, v1.x, v2.x, v3.x};
        f32x4 w1 = {v0.y, v1.y, v2.y, v3.y};
        f32x4 w2 = {v0.z, v1.z, v2.z, v3.z};
        f32x4 w3 = {v0.w, v1.w, v2.w, v3.w};
        *(f32x4*)(base + (jb + 0) * NR) = w0;
        *(f32x4*)(base + (jb + 1) * NR) = w1;
        *(f32x4*)(base + (jb + 2) * NR) = w2;
        *(f32x4*)(base + (jb + 3) * NR) = w3;
    }
    __syncthreads();

    // ---- phase 2: contiguous, aligned NT stores in output order ----
    // out offset = obase + 4*idx; LDS addr = 16*idx bytes (purely linear,
    // conflict-free b128 reads). 1296 vec4 stores per block.
    const size_t obase = (size_t)((b * ND + dd) * H + ii) * OUTROW + (size_t)j0 * NR;
    #pragma unroll
    for (int m = 0; m < 5; ++m) {
        int idx = tid + 256 * m;
        f32x4 v = *(const f32x4*)&xs[4 * idx];
        __builtin_nontemporal_store(v, (f32x4*)(out + obase + 4 * (size_t)idx));
    }
    if (tid < SUBV - 1280) {             // 16 remainder
        int idx = tid + 1280;
        f32x4 v = *(const f32x4*)&xs[4 * idx];
        __builtin_nontemporal_store(v, (f32x4*)(out + obase + 4 * (size_t)idx));
    }

    // ---- ctr output: x[b,c,40,ii,:] (done by dd==4, jc==0 blocks) ----
    if (dd == 4 && jc == 0 && tid < 96) {
        int c = tid / 24;
        int q = tid - 24 * c;
        size_t so  = (size_t)((b * NC + c) * NAA + 40) * PLANE + (size_t)ii * W + 4 * q;
        size_t dst = CTR_OFF + (size_t)((b * NC + c) * H + ii) * W + 4 * q;
        f32x4 cv = *(const f32x4*)(x + so);
        __builtin_nontemporal_store(cv, (f32x4*)(out + dst));
    }
}

extern "C" void kernel_launch(void* const* d_in, const int* in_sizes, int n_in,
                              void* d_out, int out_size, void* d_ws, size_t ws_size,
                              hipStream_t stream) {
    const float* x    = (const float*)d_in[0];
    const float* mask = (const float*)d_in[1];
    float* out = (float*)d_out;
    dim3 grid(10368, 1, 1);   // flattened; XCD-band swizzle decoded in-kernel
    build_cost_kernel<<<grid, 256, 0, stream>>>(x, mask, out);
}

// Round 8
// 237.478 us; speedup vs baseline: 1.0920x; 1.0920x over previous
//
#include <hip/hip_runtime.h>

// cost[b,dd,ii,j,c,uv] = (bounds? x[b,c,uv, ii+d*(4-u), j+d*(4-v)] : 0) * mask[b,uv,ii,j]
// d = dd-4, u=uv/9, v=uv%9.  out = cost (b,9,96,96,324) flat, then ctr = x[:,:,40,:,:].
//
// v8 = R3 + dd-merge: block = (ii, jc, b, ddg) covers dd = 3*ddg..3*ddg+2 in
// 3 passes. mask[uv, j-window] is staged in LDS ONCE and reused across
// 3 dd x 4 c = 12 uses (mask depends on neither dd nor c) -> mask global
// lane-bytes /12, total global lane-bytes -30%. Blocks 5184 -> 1728 cuts the
// measured ~2.1k-cycle per-block fixed cost (R4/R7 scaling) by 2/3. Row
// params are computed in registers per pass (no LUT LDS); LDS = 51.8 KB ->
// still 3 blocks/CU. Everything else identical to R3 (best: 241.6).

#define NAA 81
#define H 96
#define W 96
#define NC 4
#define ND 9
#define PLANE 9216          // 96*96
#define NR 324              // rows = c*81+uv
#define JB 32               // j per block
#define OUTROW 31104        // W*NR
#define CTR_OFF 53747712LL  // 2*9*96*96*324
#define XTOT 5971968        // total floats in x

typedef float f32x4 __attribute__((ext_vector_type(4)));
typedef f32x4 __attribute__((aligned(4))) f32x4u;   // 4B-aligned vector load

__global__ __launch_bounds__(512, 6)
void build_cost_kernel(const float* __restrict__ x, const float* __restrict__ mask,
                       float* __restrict__ out) {
    __shared__ __align__(16) float xs[JB * NR];    // 41,472 B output staging
    __shared__ __align__(16) float ms[NAA * JB];   // 10,368 B  ms[uv*32 + jj]

    // ---- XCD-band swizzle decode (bijective: 1728 = 8 XCD * 216) ----
    const int D   = blockIdx.x;      // 0..1727
    const int xcd = D & 7;           // target XCD (HW round-robin over dispatch id)
    const int s_  = D >> 3;          // 0..215: slot within XCD
    const int b   = s_ / 108;        // slowest: batch
    const int w_  = s_ - 108 * b;    // 0..107
    const int ddg = w_ / 36;         // slow: dd-group 0..2 (dd = 3*ddg + pass)
    const int r_  = w_ - 36 * ddg;
    const int jc  = r_ / 12;         // mid: j-chunk 0..2
    const int iio = r_ - 12 * jc;    // fast: ii within band
    const int ii  = 12 * xcd + iio;  // spatial row
    const int j0  = JB * jc;
    const int tid = threadIdx.x;

    // ---- stage mask tile once: ms[uv][jj] = mask[b,uv,ii,j0+jj] ----
    for (int idx = tid; idx < NAA * 8; idx += 512) {
        int uv = idx >> 3;
        int j4 = idx & 7;
        f32x4 mv = *(const f32x4*)(mask + ((b * NAA + uv) * H + ii) * W + j0 + 4 * j4);
        *(f32x4*)&ms[uv * JB + 4 * j4] = mv;
    }

    // ---- ctr output: x[b,c,40,ii,:] (ddg==1 blocks contain dd==4) ----
    if (ddg == 1 && jc == 0 && tid < 96) {
        int c = tid / 24;
        int q = tid - 24 * c;
        size_t so  = (size_t)((b * NC + c) * NAA + 40) * PLANE + (size_t)ii * W + 4 * q;
        size_t dst = CTR_OFF + (size_t)((b * NC + c) * H + ii) * W + 4 * q;
        f32x4 cv = *(const f32x4*)(x + so);
        __builtin_nontemporal_store(cv, (f32x4*)(out + dst));
    }
    __syncthreads();

    // ---- 3 passes: one dd each ----
    #pragma unroll
    for (int pass = 0; pass < 3; ++pass) {
        const int dd = 3 * ddg + pass;
        const int d  = dd - 4;

        // phase 1: stage 4x4 tiles. item = (row-quad rq, j-quad j4);
        // row params computed in registers (no LUT LDS).
        for (int idx = tid; idx < NAA * 8; idx += 512) {
            int rq = idx >> 3;               // row quad 0..80
            int j4 = idx & 7;                // j quad 0..7
            int jb = 4 * j4;
            f32x4 v[4];
            #pragma unroll
            for (int r = 0; r < 4; ++r) {
                int row = 4 * rq + r;        // row = c*81 + uv
                int c   = row / 81;          // magic-mul
                int uv  = row - 81 * c;
                int u   = uv / 9;
                int vv  = uv - 9 * u;
                int ri  = ii + d * (4 - u);
                int s   = d * (4 - vv);
                int col0 = j0 + jb + s;
                int xb  = ((b * NC + c) * NAA + uv) * PLANE + ri * W;
                int addr = min(max(xb + col0, 0), XTOT - 4);
                f32x4 xv = *(const f32x4u*)(x + addr);
                f32x4 mv = *(const f32x4*)&ms[uv * JB + jb];
                bool rv  = (unsigned)ri < (unsigned)H;
                v[r].x = (rv && (unsigned)(col0 + 0) < (unsigned)W) ? xv.x * mv.x : 0.0f;
                v[r].y = (rv && (unsigned)(col0 + 1) < (unsigned)W) ? xv.y * mv.y : 0.0f;
                v[r].z = (rv && (unsigned)(col0 + 2) < (unsigned)W) ? xv.z * mv.z : 0.0f;
                v[r].w = (rv && (unsigned)(col0 + 3) < (unsigned)W) ? xv.w * mv.w : 0.0f;
            }
            // transpose 4x4 in registers; column t -> rows 4rq..4rq+3 at jj=jb+t
            float* base = &xs[4 * rq];
            f32x4 w0 = {v[0].x, v[1].x, v[2].x, v[3].x};
            f32x4 w1 = {v[0].y, v[1].y, v[2].y, v[3].y};
            f32x4 w2 = {v[0].z, v[1].z, v[2].z, v[3].z};
            f32x4 w3 = {v[0].w, v[1].w, v[2].w, v[3].w};
            *(f32x4*)(base + (jb + 0) * NR) = w0;
            *(f32x4*)(base + (jb + 1) * NR) = w1;
            *(f32x4*)(base + (jb + 2) * NR) = w2;
            *(f32x4*)(base + (jb + 3) * NR) = w3;
        }
        __syncthreads();

        // phase 2: contiguous, aligned NT stores in output order.
        // out offset = obase + 4*idx; LDS addr = 16*idx bytes (linear, b128).
        const size_t obase = (size_t)((b * ND + dd) * H + ii) * OUTROW + (size_t)j0 * NR;
        for (int idx = tid; idx < NAA * JB; idx += 512) {
            f32x4 v = *(const f32x4*)&xs[4 * idx];
            __builtin_nontemporal_store(v, (f32x4*)(out + obase + 4 * (size_t)idx));
        }
        __syncthreads();
    }
}

extern "C" void kernel_launch(void* const* d_in, const int* in_sizes, int n_in,
                              void* d_out, int out_size, void* d_ws, size_t ws_size,
                              hipStream_t stream) {
    const float* x    = (const float*)d_in[0];
    const float* mask = (const float*)d_in[1];
    float* out = (float*)d_out;
    dim3 grid(1728, 1, 1);   // (ii, jc, b, ddg) flattened; XCD swizzle in-kernel
    build_cost_kernel<<<grid, 512, 0, stream>>>(x, mask, out);
}